// Round 1
// baseline (29248.499 us; speedup 1.0000x reference)
//
#include <hip/hip_runtime.h>
#include <cstdint>
#include <cstddef>

typedef __attribute__((ext_vector_type(8))) short short8;
typedef __attribute__((ext_vector_type(4))) float f32x4;

#define TT 2048
#define BB 32
#define HH 512

__device__ inline short f2bf(float f) {
  union { float f; unsigned u; } v; v.f = f;
  unsigned r = v.u + 0x7fffu + ((v.u >> 16) & 1u);
  return (short)(r >> 16);
}
__device__ inline float bf2f(short s) {
  union { unsigned u; float f; } v; v.u = ((unsigned)(unsigned short)s) << 16;
  return v.f;
}

// ---------------- weight fp32 -> bf16 conversion ----------------
__global__ void convert_weights(const float* __restrict__ w0, const float* __restrict__ w1,
                                const float* __restrict__ w2, const float* __restrict__ w3,
                                const float* __restrict__ w4, short* __restrict__ dst) {
  int i = blockIdx.x * 256 + threadIdx.x;
  if (i >= 1048576) return;
  const float* src; int off;
  if (i < 131072)      { src = w0; off = i; }
  else if (i < 393216) { src = w1; off = i - 131072; }
  else if (i < 655360) { src = w2; off = i - 393216; }
  else if (i < 917504) { src = w3; off = i - 655360; }
  else                 { src = w4; off = i - 917504; }
  dst[i] = f2bf(src[off]);
}

// ---------------- bf16 MFMA GEMM, C = A @ B^T + bias (+resid) ----------------
// A: [M,K] (fp32 or bf16), B: [N,K] bf16 row-major, C: [M,N] (bf16 or fp32)
template<int A_F32, int OUT_BF16, int RESID>
__global__ __launch_bounds__(256) void gemm_bt(const void* __restrict__ Ap,
    const short* __restrict__ Bw, const float* __restrict__ bias,
    const float* __restrict__ resid, void* __restrict__ Cp, int M, int N, int K) {
  __shared__ short As[64][40];
  __shared__ short Bs[64][40];
  int tid = threadIdx.x;
  int m0 = blockIdx.x * 64, n0 = blockIdx.y * 64;
  int w = tid >> 6, lane = tid & 63;
  int wm = w >> 1, wn = w & 1;
  int quad = lane >> 4, l16 = lane & 15;
  f32x4 acc[2][2];
#pragma unroll
  for (int i = 0; i < 2; i++)
#pragma unroll
    for (int j = 0; j < 2; j++) acc[i][j] = (f32x4){0.f, 0.f, 0.f, 0.f};
  int lr = tid >> 2, lk = (tid & 3) * 8;
  for (int kk = 0; kk < K; kk += 32) {
    __syncthreads();
    if (A_F32) {
      const float* A = (const float*)Ap;
      const float4* p = (const float4*)(A + (size_t)(m0 + lr) * K + kk + lk);
      float4 a0 = p[0], a1 = p[1];
      short8 v;
      v[0] = f2bf(a0.x); v[1] = f2bf(a0.y); v[2] = f2bf(a0.z); v[3] = f2bf(a0.w);
      v[4] = f2bf(a1.x); v[5] = f2bf(a1.y); v[6] = f2bf(a1.z); v[7] = f2bf(a1.w);
      *(short8*)&As[lr][lk] = v;
    } else {
      const short* A = (const short*)Ap;
      *(short8*)&As[lr][lk] = *(const short8*)(A + (size_t)(m0 + lr) * K + kk + lk);
    }
    *(short8*)&Bs[lr][lk] = *(const short8*)(Bw + (size_t)(n0 + lr) * K + kk + lk);
    __syncthreads();
    short8 af[2], bfr[2];
#pragma unroll
    for (int i = 0; i < 2; i++) af[i] = *(short8*)&As[wm * 32 + i * 16 + l16][quad * 8];
#pragma unroll
    for (int j = 0; j < 2; j++) bfr[j] = *(short8*)&Bs[wn * 32 + j * 16 + l16][quad * 8];
#pragma unroll
    for (int i = 0; i < 2; i++)
#pragma unroll
      for (int j = 0; j < 2; j++)
        acc[i][j] = __builtin_amdgcn_mfma_f32_16x16x32_bf16(af[i], bfr[j], acc[i][j], 0, 0, 0);
  }
#pragma unroll
  for (int i = 0; i < 2; i++) {
#pragma unroll
    for (int j = 0; j < 2; j++) {
#pragma unroll
      for (int rr = 0; rr < 4; rr++) {
        int row = m0 + wm * 32 + i * 16 + quad * 4 + rr;
        int col = n0 + wn * 32 + j * 16 + l16;
        float v2 = acc[i][j][rr] + bias[col];
        if (RESID) v2 += resid[(size_t)row * N + col];
        if (OUT_BF16) ((short*)Cp)[(size_t)row * N + col] = f2bf(v2);
        else          ((float*)Cp)[(size_t)row * N + col] = v2;
      }
    }
  }
}

// ---------------- sequential CT-RNN scan (one layer, all T steps) ----------------
// 8 WGs x 512 threads. WG g owns output cols [g*64, g*64+64).
// W-slice resident in LDS; h state fp32 in LDS (owner cols only);
// full h exchanged per step via LLC mailbox (agent-scope atomics).
__global__ __launch_bounds__(512) void seq_phase(const short* __restrict__ xin,
    const short* __restrict__ Wrec, const float* __restrict__ tau,
    int* flags, short* __restrict__ hall, unsigned int* hx) {
  __shared__ short Ws[64][520];
  __shared__ short hf[32][520];
  __shared__ float hown[32][64];
  __shared__ float rate[64];
  int g = blockIdx.x;
  int tid = threadIdx.x;
  int w = tid >> 6, lane = tid & 63;
  int mt = w & 1, nt = w >> 1;
  int quad = lane >> 4, l16 = lane & 15;

  for (int it = tid; it < 64 * 64; it += 512) {
    int rr = it >> 6, cc = (it & 63) << 3;
    *(short8*)&Ws[rr][cc] = *(const short8*)(Wrec + ((size_t)(g * 64 + rr) << 9) + cc);
  }
  for (int it = tid; it < 32 * 520; it += 512) ((short*)hf)[it] = 0;
  for (int it = tid; it < 32 * 64; it += 512) ((float*)hown)[it] = 0.f;
  if (tid < 64) {
    float tc = tau[g * 64 + tid];
    tc = fminf(fmaxf(tc, 0.1f), 10.f);
    rate[tid] = 0.1f / tc;
  }
  __syncthreads();

  int cl = nt * 16 + l16;
  float rt = rate[cl];
  const short* pxin[4]; short* ph[4]; int bidx[4];
#pragma unroll
  for (int r2 = 0; r2 < 4; r2++) {
    int b = mt * 16 + quad * 4 + r2;
    bidx[r2] = b;
    size_t base = ((size_t)b * TT) * HH + g * 64 + cl;
    pxin[r2] = xin + base;
    ph[r2] = hall + base;
  }

  for (int t = 0; t < TT; t++) {
    short xs[4];
#pragma unroll
    for (int r2 = 0; r2 < 4; r2++) xs[r2] = pxin[r2][(size_t)t * HH];
    f32x4 acc = (f32x4){0.f, 0.f, 0.f, 0.f};
#pragma unroll
    for (int kk = 0; kk < 16; kk++) {
      short8 a = *(short8*)&hf[mt * 16 + l16][kk * 32 + quad * 8];
      short8 bb = *(short8*)&Ws[nt * 16 + l16][kk * 32 + quad * 8];
      acc = __builtin_amdgcn_mfma_f32_16x16x32_bf16(a, bb, acc, 0, 0, 0);
    }
    int hxbase = (t & 1) * 32;
#pragma unroll
    for (int r2 = 0; r2 < 4; r2++) {
      float u = acc[r2] + bf2f(xs[r2]);
      float tg = tanhf(u);
      float ho = hown[bidx[r2]][cl];
      float hn = ho + rt * (tg - ho);
      hown[bidx[r2]][cl] = hn;
      short hb = f2bf(hn);
      ph[r2][(size_t)t * HH] = hb;
      unsigned int mybits = (unsigned int)(unsigned short)hb;
      unsigned int other = __shfl_xor(mybits, 1);
      if ((l16 & 1) == 0) {
        unsigned int d = mybits | (other << 16);
        __hip_atomic_store(&hx[(size_t)(hxbase + bidx[r2]) * 256 + ((g * 64 + cl) >> 1)], d,
                           __ATOMIC_RELAXED, __HIP_MEMORY_SCOPE_AGENT);
      }
    }
    __syncthreads();  // drains vmcnt: all mailbox stores complete & visible (LLC)
    if (tid == 0) {
      __hip_atomic_fetch_add(&flags[t], 1, __ATOMIC_RELEASE, __HIP_MEMORY_SCOPE_AGENT);
      while (__hip_atomic_load(&flags[t], __ATOMIC_ACQUIRE, __HIP_MEMORY_SCOPE_AGENT) < 8) {}
    }
    __syncthreads();
    {
      int b = tid >> 4, c0 = (tid & 15) * 16;
#pragma unroll
      for (int c2 = 0; c2 < 16; c2++) {
        unsigned int v = __hip_atomic_load(&hx[(size_t)(hxbase + b) * 256 + c0 + c2],
                                           __ATOMIC_RELAXED, __HIP_MEMORY_SCOPE_AGENT);
        *(unsigned int*)&hf[b][(c0 + c2) * 2] = v;
      }
    }
    __syncthreads();
  }
}

extern "C" void kernel_launch(void* const* d_in, const int* in_sizes, int n_in,
                              void* d_out, int out_size, void* d_ws, size_t ws_size,
                              hipStream_t stream) {
  const float* x      = (const float*)d_in[0];
  const float* W_in0  = (const float*)d_in[1];
  const float* b_in0  = (const float*)d_in[2];
  const float* W_rec0 = (const float*)d_in[3];
  const float* tau0   = (const float*)d_in[4];
  const float* W_in1  = (const float*)d_in[5];
  const float* b_in1  = (const float*)d_in[6];
  const float* W_rec1 = (const float*)d_in[7];
  const float* tau1   = (const float*)d_in[8];
  const float* W_out  = (const float*)d_in[9];
  const float* b_out  = (const float*)d_in[10];

  char* ws = (char*)d_ws;
  short* wb            = (short*)ws;                               // 2 MB of bf16 weights
  int* flags           = (int*)(ws + (2u << 20));                  // 16 KB
  unsigned int* hx     = (unsigned int*)(ws + (2u << 20) + (16u << 10)); // 64 KB mailbox
  short* xin           = (short*)(ws + (4u << 20));                // 64 MB
  short* hall          = (short*)(ws + (4u << 20) + (64u << 20));  // 64 MB

  short* wbin0  = wb;
  short* wbrec0 = wb + 131072;
  short* wbin1  = wb + 393216;
  short* wbrec1 = wb + 655360;
  short* wbout  = wb + 917504;

  hipMemsetAsync(flags, 0, 2 * TT * sizeof(int), stream);
  convert_weights<<<4096, 256, 0, stream>>>(W_in0, W_rec0, W_in1, W_rec1, W_out, wb);

  dim3 g1(1024, 8);
  // xin0 = x @ W_in0^T + b_in0
  gemm_bt<1, 1, 0><<<g1, 256, 0, stream>>>((const void*)x, wbin0, b_in0, nullptr,
                                           (void*)xin, BB * TT, HH, 256);
  // h0 scan
  seq_phase<<<8, 512, 0, stream>>>(xin, wbrec0, tau0, flags, hall, hx);
  // xin1 = h0_all @ W_in1^T + b_in1
  gemm_bt<0, 1, 0><<<g1, 256, 0, stream>>>((const void*)hall, wbin1, b_in1, nullptr,
                                           (void*)xin, BB * TT, HH, HH);
  // h1 scan (reuses hall buffer)
  seq_phase<<<8, 512, 0, stream>>>(xin, wbrec1, tau1, flags + TT, hall, hx);
  // out = h1_all @ W_out^T + b_out + x
  dim3 g2(1024, 4);
  gemm_bt<0, 0, 1><<<g2, 256, 0, stream>>>((const void*)hall, wbout, b_out, x,
                                           d_out, BB * TT, 256, HH);
}

// Round 2
// 14776.816 us; speedup vs baseline: 1.9794x; 1.9794x over previous
//
#include <hip/hip_runtime.h>
#include <cstdint>
#include <cstddef>

typedef __attribute__((ext_vector_type(8))) short short8;
typedef __attribute__((ext_vector_type(4))) short short4v;
typedef __attribute__((ext_vector_type(4))) float f32x4;

#define TT 2048
#define BB 32
#define HH 512

__device__ inline short f2bf(float f) {
  union { float f; unsigned u; } v; v.f = f;
  unsigned r = v.u + 0x7fffu + ((v.u >> 16) & 1u);
  return (short)(r >> 16);
}
__device__ inline float bf2f(short s) {
  union { unsigned u; float f; } v; v.u = ((unsigned)(unsigned short)s) << 16;
  return v.f;
}

// xin swizzled element index for (t, b, c):
//   wg=b>>4, bl=b&15, q=bl>>2, r=bl&3, wv=c>>6, ct=(c>>4)&3, l16=c&15, lane=q*16+l16
//   idx = ((((t*2+wg)*8+wv)*4+ct)*64 + lane)*4 + r

// ---------------- weight fp32 -> bf16 conversion ----------------
__global__ void convert_weights(const float* __restrict__ w0, const float* __restrict__ w1,
                                const float* __restrict__ w2, const float* __restrict__ w3,
                                const float* __restrict__ w4, short* __restrict__ dst) {
  int i = blockIdx.x * 256 + threadIdx.x;
  if (i >= 1048576) return;
  const float* src; int off;
  if (i < 131072)      { src = w0; off = i; }
  else if (i < 393216) { src = w1; off = i - 131072; }
  else if (i < 655360) { src = w2; off = i - 393216; }
  else if (i < 917504) { src = w3; off = i - 655360; }
  else                 { src = w4; off = i - 917504; }
  dst[i] = f2bf(src[off]);
}

// ---------------- bf16 MFMA GEMM, C = A @ B^T + bias ----------------
// A_XF32: A is fp32 x[b][t][K] with logical row m = t*32+b (remapped load)
// OUT_SW: write bf16 into swizzled xin layout; else fp32 [b][t][N] (+resid x)
template<int A_XF32, int OUT_SW, int RESID>
__global__ __launch_bounds__(256) void gemm_bt(const void* __restrict__ Ap,
    const short* __restrict__ Bw, const float* __restrict__ bias,
    const float* __restrict__ resid, void* __restrict__ Cp, int M, int N, int K) {
  __shared__ short As[64][40];
  __shared__ short Bs[64][40];
  int tid = threadIdx.x;
  int m0 = blockIdx.x * 64, n0 = blockIdx.y * 64;
  int w = tid >> 6, lane = tid & 63;
  int wm = w >> 1, wn = w & 1;
  int quad = lane >> 4, l16 = lane & 15;
  f32x4 acc[2][2];
#pragma unroll
  for (int i = 0; i < 2; i++)
#pragma unroll
    for (int j = 0; j < 2; j++) acc[i][j] = (f32x4){0.f, 0.f, 0.f, 0.f};
  int lr = tid >> 2, lk = (tid & 3) * 8;
  for (int kk = 0; kk < K; kk += 32) {
    __syncthreads();
    {
      int rl = m0 + lr;
      if (A_XF32) {
        const float* A = (const float*)Ap;
        size_t phys = ((size_t)(rl & 31) * TT + (rl >> 5)) * K;
        const float4* p = (const float4*)(A + phys + kk + lk);
        float4 a0 = p[0], a1 = p[1];
        short8 v;
        v[0] = f2bf(a0.x); v[1] = f2bf(a0.y); v[2] = f2bf(a0.z); v[3] = f2bf(a0.w);
        v[4] = f2bf(a1.x); v[5] = f2bf(a1.y); v[6] = f2bf(a1.z); v[7] = f2bf(a1.w);
        *(short8*)&As[lr][lk] = v;
      } else {
        const short* A = (const short*)Ap;
        *(short8*)&As[lr][lk] = *(const short8*)(A + (size_t)rl * K + kk + lk);
      }
      *(short8*)&Bs[lr][lk] = *(const short8*)(Bw + (size_t)(n0 + lr) * K + kk + lk);
    }
    __syncthreads();
    short8 af[2], bfr[2];
#pragma unroll
    for (int i = 0; i < 2; i++) af[i] = *(short8*)&As[wm * 32 + i * 16 + l16][quad * 8];
#pragma unroll
    for (int j = 0; j < 2; j++) bfr[j] = *(short8*)&Bs[wn * 32 + j * 16 + l16][quad * 8];
#pragma unroll
    for (int i = 0; i < 2; i++)
#pragma unroll
      for (int j = 0; j < 2; j++)
        acc[i][j] = __builtin_amdgcn_mfma_f32_16x16x32_bf16(af[i], bfr[j], acc[i][j], 0, 0, 0);
  }
#pragma unroll
  for (int i = 0; i < 2; i++) {
#pragma unroll
    for (int j = 0; j < 2; j++) {
#pragma unroll
      for (int rr = 0; rr < 4; rr++) {
        int row = m0 + wm * 32 + i * 16 + quad * 4 + rr;
        int col = n0 + wn * 32 + j * 16 + l16;
        float v2 = acc[i][j][rr] + bias[col];
        if (OUT_SW) {
          int t = row >> 5, b = row & 31;
          int wg = b >> 4, bl = b & 15, q2 = bl >> 2, r2 = bl & 3;
          int wv2 = col >> 6, ct2 = (col >> 4) & 3, lc = col & 15;
          size_t idx = (((((size_t)t * 2 + wg) * 8 + wv2) * 4 + ct2) * 64 + (q2 * 16 + lc)) * 4 + r2;
          ((short*)Cp)[idx] = f2bf(v2);
        } else {
          size_t idx = ((size_t)(row & 31) * TT + (row >> 5)) * N + col;
          if (RESID) v2 += resid[idx];
          ((float*)Cp)[idx] = v2;
        }
      }
    }
  }
}

// ---------------- single-CU-per-batch-group CT-RNN scan ----------------
// 2 WGs x 512 threads. WG wg owns batches [wg*16, wg*16+16), ALL 512 cols.
// Full W_rec resident per CU: 48 frags/wave in VGPRs + 16 frags/wave in LDS.
// h (16x512 bf16) broadcast via LDS; no cross-WG communication at all.
__global__ __launch_bounds__(512, 2) void seq_scan(
    const short* __restrict__ xin_sw, const short* __restrict__ Wrec,
    const float* __restrict__ tau, short* __restrict__ hall) {
  __shared__ short Wl[8][16][64][8];   // 128 KiB: per-wave LDS weight frags
  __shared__ short hb[16][520];        // 16.25 KiB: h state, bf16, padded rows
  int wg = blockIdx.x;
  int tid = threadIdx.x;
  int wv = tid >> 6, lane = tid & 63;
  int q = lane >> 4, l16 = lane & 15;
  int c0 = wv * 64;

  // zero h
  for (int i = tid; i < 16 * 520 / 2; i += 512) ((int*)hb)[i] = 0;

  // load weights: frags (ct, kc): B-operand = W[c0+ct*16+l16][kc*32+q*8 .. +8]
  short8 wreg[48];
#pragma unroll
  for (int ct = 0; ct < 4; ct++) {
    const short* wrow = Wrec + (size_t)(c0 + ct * 16 + l16) * HH;
#pragma unroll
    for (int kc = 0; kc < 12; kc++)
      wreg[ct * 12 + kc] = *(const short8*)(wrow + kc * 32 + q * 8);
#pragma unroll
    for (int kc = 12; kc < 16; kc++)
      *(short8*)&Wl[wv][ct * 4 + (kc - 12)][lane][0] = *(const short8*)(wrow + kc * 32 + q * 8);
  }
  float rate[4];
#pragma unroll
  for (int ct = 0; ct < 4; ct++) {
    float tc = tau[c0 + ct * 16 + l16];
    tc = fminf(fmaxf(tc, 0.1f), 10.f);
    rate[ct] = 0.1f / tc;
  }
  float st[16];
#pragma unroll
  for (int i = 0; i < 16; i++) st[i] = 0.f;

  // prefetch xin for t=0
  short4v xr[4];
#pragma unroll
  for (int ct = 0; ct < 4; ct++)
    xr[ct] = *(const short4v*)(xin_sw + ((((size_t)0 * 2 + wg) * 8 + wv) * 4 + ct) * 256 + lane * 4);
  __syncthreads();

  for (int t = 0; t < TT; t++) {
    f32x4 acc[4];
#pragma unroll
    for (int ct = 0; ct < 4; ct++) acc[ct] = (f32x4){0.f, 0.f, 0.f, 0.f};
#pragma unroll
    for (int kc = 0; kc < 16; kc++) {
      short8 af = *(short8*)&hb[l16][kc * 32 + q * 8];
#pragma unroll
      for (int ct = 0; ct < 4; ct++) {
        short8 wf;
        if (kc < 12) wf = wreg[ct * 12 + kc];
        else wf = *(short8*)&Wl[wv][ct * 4 + (kc - 12)][lane][0];
        acc[ct] = __builtin_amdgcn_mfma_f32_16x16x32_bf16(af, wf, acc[ct], 0, 0, 0);
      }
    }
    __syncthreads();  // all waves done reading hb[t]
    // epilogue: u = acc + xin; h += rate*(tanh(u)-h)
#pragma unroll
    for (int ct = 0; ct < 4; ct++) {
#pragma unroll
      for (int r = 0; r < 4; r++) {
        float u = acc[ct][r] + bf2f(xr[ct][r]);
        float a = fabsf(u);
        float e = exp2f(a * 2.8853900817779268f);   // e^{2|u|}
        float tg = copysignf(1.f - 2.f / (e + 1.f), u);
        float h = st[ct * 4 + r];
        h += rate[ct] * (tg - h);
        st[ct * 4 + r] = h;
        hb[q * 4 + r][c0 + ct * 16 + l16] = f2bf(h);
      }
    }
    // prefetch xin for t+1 (consumed next epilogue; full step of latency slack)
    if (t + 1 < TT) {
#pragma unroll
      for (int ct = 0; ct < 4; ct++)
        xr[ct] = *(const short4v*)(xin_sw + ((((size_t)(t + 1) * 2 + wg) * 8 + wv) * 4 + ct) * 256 + lane * 4);
    }
    __syncthreads();  // hb[t+1] complete
    // coalesced copy hb -> hall (time-major row t*32 + wg*16 + bl)
#pragma unroll
    for (int it = 0; it < 2; it++) {
      int ci = it * 512 + tid;
      int bl = ci >> 6, off = (ci & 63) * 8;
      short8 v = *(short8*)&hb[bl][off];
      *(short8*)(hall + ((size_t)t * 32 + wg * 16 + bl) * HH + off) = v;
    }
  }
}

extern "C" void kernel_launch(void* const* d_in, const int* in_sizes, int n_in,
                              void* d_out, int out_size, void* d_ws, size_t ws_size,
                              hipStream_t stream) {
  const float* x      = (const float*)d_in[0];
  const float* W_in0  = (const float*)d_in[1];
  const float* b_in0  = (const float*)d_in[2];
  const float* W_rec0 = (const float*)d_in[3];
  const float* tau0   = (const float*)d_in[4];
  const float* W_in1  = (const float*)d_in[5];
  const float* b_in1  = (const float*)d_in[6];
  const float* W_rec1 = (const float*)d_in[7];
  const float* tau1   = (const float*)d_in[8];
  const float* W_out  = (const float*)d_in[9];
  const float* b_out  = (const float*)d_in[10];

  char* ws = (char*)d_ws;
  short* wb     = (short*)ws;                        // 2 MB bf16 weights
  short* xin_sw = (short*)(ws + (4u << 20));         // 64 MB swizzled xin
  short* hall   = (short*)(ws + (68u << 20));        // 64 MB h stream (t-major)

  short* wbin0  = wb;
  short* wbrec0 = wb + 131072;
  short* wbin1  = wb + 393216;
  short* wbrec1 = wb + 655360;
  short* wbout  = wb + 917504;

  convert_weights<<<4096, 256, 0, stream>>>(W_in0, W_rec0, W_in1, W_rec1, W_out, wb);

  dim3 g1(1024, 8);
  // xin0 = x @ W_in0^T + b_in0  (swizzled bf16)
  gemm_bt<1, 1, 0><<<g1, 256, 0, stream>>>((const void*)x, wbin0, b_in0, nullptr,
                                           (void*)xin_sw, BB * TT, HH, 256);
  // layer-0 scan -> hall (h0, time-major)
  seq_scan<<<2, 512, 0, stream>>>(xin_sw, wbrec0, tau0, hall);
  // xin1 = h0 @ W_in1^T + b_in1  (swizzled bf16)
  gemm_bt<0, 1, 0><<<g1, 256, 0, stream>>>((const void*)hall, wbin1, b_in1, nullptr,
                                           (void*)xin_sw, BB * TT, HH, HH);
  // layer-1 scan -> hall (h1)
  seq_scan<<<2, 512, 0, stream>>>(xin_sw, wbrec1, tau1, hall);
  // out = h1 @ W_out^T + b_out + x  (fp32, [b][t][c])
  dim3 g2(1024, 4);
  gemm_bt<0, 0, 1><<<g2, 256, 0, stream>>>((const void*)hall, wbout, b_out, x,
                                           d_out, BB * TT, 256, HH);
}